// Round 13
// baseline (248.231 us; speedup 1.0000x reference)
//
#include <hip/hip_runtime.h>
#include <math.h>

// ---------------------------------------------------------------------------
// Fused YaRN-GQA attention block, bf16 MFMA pipeline.
// R13: GEMM reverted to R9's exact 2-phase double-buffered 128² kernel
//      (counted-vmcnt graft was neutral/negative). attn switched to the
//      jq2 body (32 q-rows/wave, Q-tile 128 — halves LDS instr per q-row;
//      correctness-proven in R5) with a dispatch-order-robust alternating
//      qt map replacing R5's falsified (bid,bid+256) pairing.
// ---------------------------------------------------------------------------

typedef __attribute__((ext_vector_type(8))) short s16x8;
typedef __attribute__((ext_vector_type(4))) float f32x4;
typedef __attribute__((ext_vector_type(4))) unsigned int u32x4;

__device__ __forceinline__ unsigned short f2bf(float x) {
  union { float f; unsigned int u; } v; v.f = x;
  return (unsigned short)((v.u + 0x7FFFu + ((v.u >> 16) & 1u)) >> 16);
}

__device__ __forceinline__ float bf2f(unsigned short x) {
  union { unsigned int u; float f; } v; v.u = (unsigned int)x << 16;
  return v.f;
}

__device__ __forceinline__ unsigned int cvt_pk_bf16(float lo, float hi) {
  unsigned int r;
  asm("v_cvt_pk_bf16_f32 %0, %1, %2" : "=v"(r) : "v"(lo), "v"(hi));
  return r;
}

#define GLD_LDS16(g, l)                                            \
  __builtin_amdgcn_global_load_lds(                                \
      (const __attribute__((address_space(1))) void*)(g),          \
      (__attribute__((address_space(3))) void*)(l), 16, 0, 0)

// ---------------- cast x (fp32) -> bf16, 4 elems/thread ----------------
__global__ __launch_bounds__(256) void cast_bf16_k(const float* __restrict__ in,
                                                   unsigned short* __restrict__ out) {
  int i = blockIdx.x * 256 + threadIdx.x;
  float4 v = ((const float4*)in)[i];
  unsigned long long pack = (unsigned long long)f2bf(v.x)
                          | ((unsigned long long)f2bf(v.y) << 16)
                          | ((unsigned long long)f2bf(v.z) << 32)
                          | ((unsigned long long)f2bf(v.w) << 48);
  ((unsigned long long*)out)[i] = pack;
}

// ---------------- W (RxC fp32 row-major) -> Wt (CxR bf16) ----------------
__global__ __launch_bounds__(256) void wtrans_k(const float* __restrict__ in,
                                                unsigned short* __restrict__ out,
                                                int R, int C) {
  __shared__ unsigned short lt[64][65];
  const int r0 = blockIdx.x * 64, c0 = blockIdx.y * 64;
  const int j = threadIdx.x & 63, i4 = threadIdx.x >> 6;
#pragma unroll
  for (int p = 0; p < 16; ++p) {
    int i = p * 4 + i4;
    lt[i][j] = f2bf(in[(size_t)(r0 + i) * C + c0 + j]);
  }
  __syncthreads();
#pragma unroll
  for (int p = 0; p < 16; ++p) {
    int i = p * 4 + i4;
    out[(size_t)(c0 + i) * R + r0 + j] = lt[j][i];
  }
}

// ---------------- trig table: cstab[t*64+f] = (cos, sin)(t*invf[f]) ----------
__global__ __launch_bounds__(256) void trig_k(const float* __restrict__ invf,
                                              float2* __restrict__ cstab) {
  int i = blockIdx.x * 256 + threadIdx.x;   // < 2048*64
  int t = i >> 6, f = i & 63;
  float s, c;
  sincosf((float)t * invf[f], &s, &c);
  cstab[i] = make_float2(c, s);
}

// ---------------- GEMM (R9): C = A @ Bt^T, bf16 in, fp32 or bf16 out ---------
// 128x128 tile, 4 waves, BK=32. 2-phase double-buffered loop: STAGE(t+1)
// issued first, ds_read+MFMA on t, single barrier/iter. T2 slot-XOR swizzle
// pre-applied at global source and on the fragment read.
template <int OUTBF>
__global__ __launch_bounds__(256) void gemm_bt_t(const unsigned short* __restrict__ A,
                                                 const unsigned short* __restrict__ Bt,
                                                 void* __restrict__ Cv,
                                                 int M, int N, int K) {
  __shared__ alignas(16) unsigned short sA[2][128][32];
  __shared__ alignas(16) unsigned short sB[2][128][32];
  const int tid = threadIdx.x;
  const int lane = tid & 63;
  const int w = tid >> 6;
  const int wm = (w >> 1) * 64, wn = (w & 1) * 64;
  const int nwg = gridDim.x * gridDim.y;
  int bid = blockIdx.y * gridDim.x + blockIdx.x;
  bid = (bid & 7) * (nwg >> 3) + (bid >> 3);
  const int m0 = (bid % gridDim.x) * 128, n0 = (bid / gridDim.x) * 128;
  const int l15 = lane & 15, lhi = lane >> 4;
  f32x4 acc[4][4];
#pragma unroll
  for (int i = 0; i < 4; ++i)
#pragma unroll
    for (int j = 0; j < 4; ++j) acc[i][j] = (f32x4){0.f, 0.f, 0.f, 0.f};
  const int row = tid >> 2;
  const int srcslot = (tid & 3) ^ ((row >> 1) & 3);
  const unsigned short* gA0 = A + (size_t)(m0 + row) * K + srcslot * 8;
  const unsigned short* gA1 = A + (size_t)(m0 + 64 + row) * K + srcslot * 8;
  const unsigned short* gB0 = Bt + (size_t)(n0 + row) * K + srcslot * 8;
  const unsigned short* gB1 = Bt + (size_t)(n0 + 64 + row) * K + srcslot * 8;
  char* ldsA = (char*)&sA[0][0][0] + w * 1024;   // wave-uniform; HW adds lane*16
  char* ldsB = (char*)&sB[0][0][0] + w * 1024;
  auto STAGE = [&](int bb, int k0) {
    GLD_LDS16(gA0 + k0, ldsA + bb * 8192);
    GLD_LDS16(gA1 + k0, ldsA + bb * 8192 + 4096);
    GLD_LDS16(gB0 + k0, ldsB + bb * 8192);
    GLD_LDS16(gB1 + k0, ldsB + bb * 8192 + 4096);
  };
  const int sphys = (lhi ^ ((l15 >> 1) & 3)) * 8;
  const int nt = K >> 5;
  STAGE(0, 0);
  __syncthreads();                       // drains vmcnt -> buf0 ready
  int cur = 0;
  for (int t = 0; t < nt; ++t) {
    if (t + 1 < nt) STAGE(cur ^ 1, (t + 1) * 32);
    s16x8 af[4], bfr[4];
#pragma unroll
    for (int i = 0; i < 4; ++i) af[i] = *(const s16x8*)&sA[cur][wm + i * 16 + l15][sphys];
#pragma unroll
    for (int j = 0; j < 4; ++j) bfr[j] = *(const s16x8*)&sB[cur][wn + j * 16 + l15][sphys];
#pragma unroll
    for (int i = 0; i < 4; ++i)
#pragma unroll
      for (int j = 0; j < 4; ++j)
        acc[i][j] = __builtin_amdgcn_mfma_f32_16x16x32_bf16(af[i], bfr[j], acc[i][j], 0, 0, 0);
    __syncthreads();                     // drains vmcnt(0): next buf landed
    cur ^= 1;
  }
  const int col0 = n0 + wn + l15;
  const int row00 = m0 + wm + lhi * 4;
  if (OUTBF) {
    unsigned short* C = (unsigned short*)Cv;
#pragma unroll
    for (int i = 0; i < 4; ++i)
#pragma unroll
      for (int j = 0; j < 4; ++j)
#pragma unroll
        for (int r = 0; r < 4; ++r)
          C[(size_t)(row00 + i * 16 + r) * N + col0 + j * 16] = f2bf(acc[i][j][r]);
  } else {
    float* C = (float*)Cv;
#pragma unroll
    for (int i = 0; i < 4; ++i)
#pragma unroll
      for (int j = 0; j < 4; ++j)
#pragma unroll
        for (int r = 0; r < 4; ++r)
          C[(size_t)(row00 + i * 16 + r) * N + col0 + j * 16] = acc[i][j][r];
  }
}

// ---------------- RMSNorm + RoPE + pack (one wave per 128-vec) ----------------
// qkvb (bf16) row layout: [0,2048) q heads | [2048,2560) k | [2560,3072) v
__global__ __launch_bounds__(256) void normrope_k(const unsigned short* __restrict__ qkvb,
                                                  const float* __restrict__ qw,
                                                  const float* __restrict__ kw,
                                                  const float2* __restrict__ cstab,
                                                  unsigned short* __restrict__ qT,
                                                  unsigned short* __restrict__ kT) {
  constexpr float FOLD =
      (float)(1.4426950408889634 / ((0.1 * 0.6931471805599453 + 1.0) * 11.313708498984761));
  int wid = blockIdx.x * 4 + (threadIdx.x >> 6);
  int lane = threadIdx.x & 63;
  const unsigned short* src; const float* wgt; unsigned short* dst;
  int t; float fold;
  if (wid < 65536) {
    int bt = wid >> 4, h = wid & 15;
    int b = bt >> 11; t = bt & 2047;
    src = qkvb + (size_t)bt * 3072 + h * 128;
    wgt = qw;
    dst = qT + ((size_t)(b * 16 + h) * 2048 + t) * 128;
    fold = FOLD;
  } else {
    int id = wid - 65536;
    int bt = id >> 2, g = id & 3;
    int b = bt >> 11; t = bt & 2047;
    src = qkvb + (size_t)bt * 3072 + 2048 + g * 128;
    wgt = kw;
    dst = kT + ((size_t)(b * 4 + g) * 2048 + t) * 128;
    fold = 1.0f;
  }
  unsigned int vv = ((const unsigned int*)src)[lane];   // 2 bf16: d=2*lane, 2*lane+1
  float vx = bf2f((unsigned short)(vv & 0xffff));
  float vy = bf2f((unsigned short)(vv >> 16));
  float ss = vx * vx + vy * vy;
#pragma unroll
  for (int m = 32; m; m >>= 1) ss += __shfl_xor(ss, m);
  float rs = rsqrtf(ss * (1.0f / 128.0f) + 1.1920929e-07f);
  float2 wv = ((const float2*)wgt)[lane];
  float xn0 = vx * rs * wv.x;
  float xn1 = vy * rs * wv.y;
  float px = __shfl_xor(xn0, 32);
  float py = __shfl_xor(xn1, 32);
  float sgn = (lane < 32) ? -1.0f : 1.0f;
  int f0 = (2 * lane) & 63;
  float4 cs = ((const float4*)cstab)[((size_t)t * 64 + f0) >> 1];
  float r0 = (xn0 * cs.x + sgn * px * cs.y) * fold;
  float r1 = (xn1 * cs.z + sgn * py * cs.w) * fold;
  unsigned int packed = (unsigned int)f2bf(r0) | ((unsigned int)f2bf(r1) << 16);
  ((unsigned int*)dst)[lane] = packed;
}

// ---------------- v (bf16) -> vT[b,g,d,t'] bf16, t' pi-permuted --------------
__global__ __launch_bounds__(256) void vtrans_k(const unsigned short* __restrict__ qkvb,
                                                unsigned short* __restrict__ vT) {
  __shared__ unsigned short lt[64][65];
  const int tt0 = blockIdx.x * 64;
  const int dd0 = blockIdx.y * 64;
  const int b = blockIdx.z >> 2, g = blockIdx.z & 3;
  const int j = threadIdx.x & 63, i4 = threadIdx.x >> 6;
  const unsigned short* src = qkvb + (size_t)b * 2048 * 3072 + 2560 + g * 128 + dd0;
#pragma unroll
  for (int p = 0; p < 16; ++p) {
    int i = p * 4 + i4;
    lt[i][j] = src[(size_t)(tt0 + i) * 3072 + j];
  }
  __syncthreads();
  unsigned short* dst = vT + ((size_t)(b * 4 + g) * 128 + dd0) * 2048 + tt0;
  const int jp = (j & 32) | (((j & 15) >> 2) << 3) | (((j >> 4) & 1) << 2) | (j & 3);
#pragma unroll
  for (int p = 0; p < 16; ++p) {
    int d = p * 4 + i4;
    dst[(size_t)d * 2048 + jp] = lt[j][d];
  }
}

// ---------------- causal flash attention (jq2 body, R5-proven) ---------------
// 4 waves x 32 q-rows (Q-tile 128), kt tiles of 64. K/V frag reads shared
// across two Q sub-blocks per wave (halves LDS instrs per q-row).
// Grid 512: bid%8 = b*4+g (XCD pin); qt map alternates heavy/light groups
// in dispatch order (u even -> 15-u/2 heavy, u odd -> u/2 light) so any
// contiguous in-flight window mixes block weights; backfill balances.
__global__ __launch_bounds__(256) void attn_k(const unsigned short* __restrict__ qT,
                                              const unsigned short* __restrict__ kT,
                                              const unsigned short* __restrict__ vT,
                                              unsigned short* __restrict__ ao) {
  __shared__ alignas(16) unsigned short sK[64][136];
  __shared__ alignas(16) unsigned short sVt[128][72];
  const int tid = threadIdx.x;
  const int lane = tid & 63;
  const int w = tid >> 6;
  const int l15 = lane & 15, lhi = lane >> 4;
  const int bid = blockIdx.x;              // 0..511
  const int colc = bid & 31;               // column code (bid%8 = b*4+g)
  const int u = bid >> 5;                  // 0..15
  const int qt = (u & 1) ? (u >> 1) : 15 - (u >> 1);
  const int b = (colc >> 2) & 1, g = colc & 3;
  const int h = (colc >> 3) * 4 + g;
  const int q0 = qt * 128;
  const unsigned short* Qb = qT + ((size_t)(b * 16 + h) * 2048) * 128;
  const unsigned short* Kb = kT + ((size_t)(b * 4 + g) * 2048) * 128;
  const unsigned short* Vb = vT + ((size_t)(b * 4 + g) * 128) * 2048;
  const int kr = tid >> 4, kc = (tid & 15) * 8;
  const int vr = tid >> 3, vc = (tid & 7) * 8;

  // Q fragments straight from global (L2): B-frag col=l15 (qrow), k=d slice
  s16x8 qfr[2][4];
#pragma unroll
  for (int jq = 0; jq < 2; ++jq)
#pragma unroll
    for (int ks = 0; ks < 4; ++ks)
      qfr[jq][ks] = *(const s16x8*)(Qb +
          (size_t)(q0 + w * 32 + jq * 16 + l15) * 128 + ks * 32 + lhi * 8);
  // prefetch kt=0 K/V into regs
  u32x4 gk[4], gv[4];
#pragma unroll
  for (int p = 0; p < 4; ++p) {
    gk[p] = *(const u32x4*)(Kb + (size_t)(p * 16 + kr) * 128 + kc);
    gv[p] = *(const u32x4*)(Vb + (size_t)(p * 32 + vr) * 2048 + vc);
  }
  f32x4 o[2][8];
#pragma unroll
  for (int jq = 0; jq < 2; ++jq)
#pragma unroll
    for (int i = 0; i < 8; ++i) o[jq][i] = (f32x4){0.f, 0.f, 0.f, 0.f};
  f32x4 o9[2] = {(f32x4){0.f, 0.f, 0.f, 0.f}, (f32x4){0.f, 0.f, 0.f, 0.f}};
  float m_run[2] = {-INFINITY, -INFINITY};
  s16x8 ones;
#pragma unroll
  for (int j = 0; j < 8; ++j) ones[j] = (short)0x3F80;  // bf16 1.0

  const int ktmax = 2 * qt + 1;
  for (int kt = 0; kt <= ktmax; ++kt) {
    __syncthreads();
#pragma unroll
    for (int p = 0; p < 4; ++p) {
      *(u32x4*)&sK[p * 16 + kr][kc] = gk[p];
      *(u32x4*)&sVt[p * 32 + vr][vc] = gv[p];
    }
    __syncthreads();
    if (kt < ktmax) {                      // T14: issue next-tile loads early
#pragma unroll
      for (int p = 0; p < 4; ++p) {
        gk[p] = *(const u32x4*)(Kb + (size_t)((kt + 1) * 64 + p * 16 + kr) * 128 + kc);
        gv[p] = *(const u32x4*)(Vb + (size_t)(p * 32 + vr) * 2048 + (kt + 1) * 64 + vc);
      }
    }
    // S^T: s[jq][jn][r] = S[qrow = q0+w*32+jq*16+l15][kpos = kt*64+jn*16+lhi*4+r]
    f32x4 s[2][4];
#pragma unroll
    for (int jq = 0; jq < 2; ++jq)
#pragma unroll
      for (int jn = 0; jn < 4; ++jn) s[jq][jn] = (f32x4){0.f, 0.f, 0.f, 0.f};
#pragma unroll
    for (int ks = 0; ks < 4; ++ks)
#pragma unroll
      for (int jn = 0; jn < 4; ++jn) {
        s16x8 ak = *(const s16x8*)&sK[jn * 16 + l15][ks * 32 + lhi * 8];
        s[0][jn] = __builtin_amdgcn_mfma_f32_16x16x32_bf16(ak, qfr[0][ks], s[0][jn], 0, 0, 0);
        s[1][jn] = __builtin_amdgcn_mfma_f32_16x16x32_bf16(ak, qfr[1][ks], s[1][jn], 0, 0, 0);
      }
    if (kt >= 2 * qt) {                    // tiles intersecting the diagonal
#pragma unroll
      for (int jq = 0; jq < 2; ++jq)
#pragma unroll
        for (int jn = 0; jn < 4; ++jn)
#pragma unroll
          for (int r = 0; r < 4; ++r)
            if (kt * 64 + jn * 16 + lhi * 4 + r > q0 + w * 32 + jq * 16 + l15)
              s[jq][jn][r] = -INFINITY;
    }
    // row max per jq (per-lane row) + reduce across the 4 lhi copies
    float mx[2];
#pragma unroll
    for (int jq = 0; jq < 2; ++jq) {
      float m = fmaxf(fmaxf(fmaxf(s[jq][0][0], s[jq][0][1]), fmaxf(s[jq][0][2], s[jq][0][3])),
                      fmaxf(fmaxf(s[jq][1][0], s[jq][1][1]), fmaxf(s[jq][1][2], s[jq][1][3])));
      m = fmaxf(m, fmaxf(fmaxf(fmaxf(s[jq][2][0], s[jq][2][1]), fmaxf(s[jq][2][2], s[jq][2][3])),
                         fmaxf(fmaxf(s[jq][3][0], s[jq][3][1]), fmaxf(s[jq][3][2], s[jq][3][3]))));
      m = fmaxf(m, __shfl_xor(m, 16));
      m = fmaxf(m, __shfl_xor(m, 32));
      mx[jq] = m;
    }
    // T13 defer-max: rescale only when a max grew past threshold (exp2 units)
    if (!__all(fmaxf(mx[0] - m_run[0], mx[1] - m_run[1]) <= 8.0f)) {
#pragma unroll
      for (int jq = 0; jq < 2; ++jq) {
        float mnew = fmaxf(m_run[jq], mx[jq]);
        float scale = exp2f(m_run[jq] - mnew);
        m_run[jq] = mnew;
        float sc_o[4];
#pragma unroll
        for (int r = 0; r < 4; ++r) sc_o[r] = __shfl(scale, lhi * 4 + r);
#pragma unroll
        for (int nt = 0; nt < 8; ++nt)
#pragma unroll
          for (int r = 0; r < 4; ++r) o[jq][nt][r] *= sc_o[r];
#pragma unroll
        for (int r = 0; r < 4; ++r) o9[jq][r] *= sc_o[r];
      }
    }
    // P = exp2(S - m); pack to bf16 A-frags via cvt_pk; l-sum via ones-MFMA
    union { s16x8 v; unsigned int d[4]; } pa[2][2];
#pragma unroll
    for (int jq = 0; jq < 2; ++jq) {
      float pp[4][4];
#pragma unroll
      for (int jn = 0; jn < 4; ++jn)
#pragma unroll
        for (int r = 0; r < 4; ++r) pp[jn][r] = exp2f(s[jq][jn][r] - m_run[jq]);
#pragma unroll
      for (int d = 0; d < 2; ++d) {
        pa[jq][0].d[d]     = cvt_pk_bf16(pp[0][2 * d], pp[0][2 * d + 1]);
        pa[jq][0].d[2 + d] = cvt_pk_bf16(pp[1][2 * d], pp[1][2 * d + 1]);
        pa[jq][1].d[d]     = cvt_pk_bf16(pp[2][2 * d], pp[2][2 * d + 1]);
        pa[jq][1].d[2 + d] = cvt_pk_bf16(pp[3][2 * d], pp[3][2 * d + 1]);
      }
      o9[jq] = __builtin_amdgcn_mfma_f32_16x16x32_bf16(pa[jq][0].v, ones, o9[jq], 0, 0, 0);
      o9[jq] = __builtin_amdgcn_mfma_f32_16x16x32_bf16(pa[jq][1].v, ones, o9[jq], 0, 0, 0);
    }
    // O += P V  (V frag reads shared across jq)
#pragma unroll
    for (int nt = 0; nt < 8; ++nt) {
      s16x8 vb0 = *(const s16x8*)&sVt[nt * 16 + l15][lhi * 8];
      o[0][nt] = __builtin_amdgcn_mfma_f32_16x16x32_bf16(pa[0][0].v, vb0, o[0][nt], 0, 0, 0);
      o[1][nt] = __builtin_amdgcn_mfma_f32_16x16x32_bf16(pa[1][0].v, vb0, o[1][nt], 0, 0, 0);
    }
#pragma unroll
    for (int nt = 0; nt < 8; ++nt) {
      s16x8 vb1 = *(const s16x8*)&sVt[nt * 16 + l15][32 + lhi * 8];
      o[0][nt] = __builtin_amdgcn_mfma_f32_16x16x32_bf16(pa[0][1].v, vb1, o[0][nt], 0, 0, 0);
      o[1][nt] = __builtin_amdgcn_mfma_f32_16x16x32_bf16(pa[1][1].v, vb1, o[1][nt], 0, 0, 0);
    }
  }
  // epilogue: o9[jq][r] is the row-sum for row lhi*4+r of sub-block jq
#pragma unroll
  for (int jq = 0; jq < 2; ++jq)
#pragma unroll
    for (int r = 0; r < 4; ++r) {
      float invr = 1.0f / o9[jq][r];
      int t = q0 + w * 32 + jq * 16 + lhi * 4 + r;
      size_t base = ((size_t)b * 2048 + t) * 2048 + h * 128;
#pragma unroll
      for (int nt = 0; nt < 8; ++nt)
        ao[base + nt * 16 + l15] = f2bf(o[jq][nt][r] * invr);
    }
}

// ---------------------------------------------------------------------------
extern "C" void kernel_launch(void* const* d_in, const int* in_sizes, int n_in,
                              void* d_out, int out_size, void* d_ws, size_t ws_size,
                              hipStream_t stream) {
  (void)in_sizes; (void)n_in; (void)out_size; (void)ws_size;
  const float* x    = (const float*)d_in[0];
  const float* Wq   = (const float*)d_in[1];
  const float* Wkv  = (const float*)d_in[2];
  const float* Wout = (const float*)d_in[3];
  const float* qw   = (const float*)d_in[4];
  const float* kw   = (const float*)d_in[5];
  const float* invf = (const float*)d_in[6];
  float* out = (float*)d_out;

  char* ws = (char*)d_ws;
  size_t off = 0;
  auto alloc = [&](size_t bytes) -> void* {
    void* p = ws + off; off += (bytes + 255) & ~(size_t)255; return p;
  };
  unsigned short* xb    = (unsigned short*)alloc((size_t)4096 * 2048 * 2);
  unsigned short* wqkvt = (unsigned short*)alloc((size_t)3072 * 2048 * 2);
  unsigned short* wot   = (unsigned short*)alloc((size_t)2048 * 2048 * 2);
  unsigned short* qkvb  = (unsigned short*)alloc((size_t)4096 * 3072 * 2);
  float2* cstab = (float2*)alloc((size_t)2048 * 64 * 8);
  unsigned short* qT = (unsigned short*)alloc((size_t)2 * 16 * 2048 * 128 * 2);
  unsigned short* kT = (unsigned short*)alloc((size_t)2 * 4 * 2048 * 128 * 2);
  unsigned short* vT = (unsigned short*)alloc((size_t)2 * 4 * 128 * 2048 * 2);
  unsigned short* ao = (unsigned short*)alloc((size_t)4096 * 2048 * 2);

  cast_bf16_k<<<8192, 256, 0, stream>>>(x, xb);
  wtrans_k<<<dim3(32, 32), 256, 0, stream>>>(Wq, wqkvt, 2048, 2048);
  wtrans_k<<<dim3(32, 16), 256, 0, stream>>>(Wkv, wqkvt + (size_t)2048 * 2048, 2048, 1024);
  wtrans_k<<<dim3(32, 32), 256, 0, stream>>>(Wout, wot, 2048, 2048);
  trig_k<<<512, 256, 0, stream>>>(invf, cstab);
  gemm_bt_t<1><<<dim3(32, 24), 256, 0, stream>>>(xb, wqkvt, qkvb, 4096, 3072, 2048);
  normrope_k<<<20480, 256, 0, stream>>>(qkvb, qw, kw, cstab, qT, kT);
  vtrans_k<<<dim3(32, 2, 8), 256, 0, stream>>>(qkvb, vT);
  attn_k<<<512, 256, 0, stream>>>(qT, kT, vT, ao);
  gemm_bt_t<0><<<dim3(32, 16), 256, 0, stream>>>(ao, wot, out, 4096, 2048, 2048);
}

// Round 14
// 212.413 us; speedup vs baseline: 1.1686x; 1.1686x over previous
//
#include <hip/hip_runtime.h>
#include <math.h>

// ---------------------------------------------------------------------------
// Fused YaRN-GQA attention block, bf16 MFMA pipeline.
// R14: attn reverted to R9 (best measured: 85us; jq2 direction closed after
//      3 failures). GEMM = R9 2-phase. Prep kernels fused: prep1 = cast +
//      3x wtrans + trig; prep2 = normrope + vtrans (launches 10 -> 6).
// ---------------------------------------------------------------------------

typedef __attribute__((ext_vector_type(8))) short s16x8;
typedef __attribute__((ext_vector_type(4))) float f32x4;
typedef __attribute__((ext_vector_type(4))) unsigned int u32x4;

__device__ __forceinline__ unsigned short f2bf(float x) {
  union { float f; unsigned int u; } v; v.f = x;
  return (unsigned short)((v.u + 0x7FFFu + ((v.u >> 16) & 1u)) >> 16);
}

__device__ __forceinline__ float bf2f(unsigned short x) {
  union { unsigned int u; float f; } v; v.u = (unsigned int)x << 16;
  return v.f;
}

__device__ __forceinline__ unsigned int cvt_pk_bf16(float lo, float hi) {
  unsigned int r;
  asm("v_cvt_pk_bf16_f32 %0, %1, %2" : "=v"(r) : "v"(lo), "v"(hi));
  return r;
}

#define GLD_LDS16(g, l)                                            \
  __builtin_amdgcn_global_load_lds(                                \
      (const __attribute__((address_space(1))) void*)(g),          \
      (__attribute__((address_space(3))) void*)(l), 16, 0, 0)

// ---------------- prep1: cast x->bf16 | Wq^T | Wkv^T | Wout^T | trig --------
// block ranges: [0,8192) cast, [8192,9216) Wq, [9216,9728) Wkv,
//               [9728,10752) Wout, [10752,11264) trig
__device__ __forceinline__ void wtrans_body(const float* __restrict__ in,
                                            unsigned short* __restrict__ out,
                                            int R, int C, int bx, int by,
                                            unsigned short lt[64][65]) {
  const int r0 = bx * 64, c0 = by * 64;
  const int j = threadIdx.x & 63, i4 = threadIdx.x >> 6;
#pragma unroll
  for (int p = 0; p < 16; ++p) {
    int i = p * 4 + i4;
    lt[i][j] = f2bf(in[(size_t)(r0 + i) * C + c0 + j]);
  }
  __syncthreads();
#pragma unroll
  for (int p = 0; p < 16; ++p) {
    int i = p * 4 + i4;
    out[(size_t)(c0 + i) * R + r0 + j] = lt[j][i];
  }
}

__global__ __launch_bounds__(256) void prep1_k(const float* __restrict__ x,
                                               const float* __restrict__ Wq,
                                               const float* __restrict__ Wkv,
                                               const float* __restrict__ Wout,
                                               const float* __restrict__ invf,
                                               unsigned short* __restrict__ xb,
                                               unsigned short* __restrict__ wqkvt,
                                               unsigned short* __restrict__ wot,
                                               float2* __restrict__ cstab) {
  __shared__ unsigned short lt[64][65];
  const int bid = blockIdx.x;
  if (bid < 8192) {                        // cast: 4 fp32 -> 4 bf16 per thread
    int i = bid * 256 + threadIdx.x;
    float4 v = ((const float4*)x)[i];
    unsigned long long pack = (unsigned long long)f2bf(v.x)
                            | ((unsigned long long)f2bf(v.y) << 16)
                            | ((unsigned long long)f2bf(v.z) << 32)
                            | ((unsigned long long)f2bf(v.w) << 48);
    ((unsigned long long*)xb)[i] = pack;
  } else if (bid < 9216) {                 // Wq (2048x2048) -> wqkvt[0:2048]
    int b2 = bid - 8192;
    wtrans_body(Wq, wqkvt, 2048, 2048, b2 & 31, b2 >> 5, lt);
  } else if (bid < 9728) {                 // Wkv (2048x1024) -> wqkvt[2048:]
    int b2 = bid - 9216;
    wtrans_body(Wkv, wqkvt + (size_t)2048 * 2048, 2048, 1024, b2 & 31, b2 >> 5, lt);
  } else if (bid < 10752) {                // Wout (2048x2048) -> wot
    int b2 = bid - 9728;
    wtrans_body(Wout, wot, 2048, 2048, b2 & 31, b2 >> 5, lt);
  } else {                                 // trig table
    int i = (bid - 10752) * 256 + threadIdx.x;   // < 2048*64
    int t = i >> 6, f = i & 63;
    float s, c;
    sincosf((float)t * invf[f], &s, &c);
    cstab[i] = make_float2(c, s);
  }
}

// ---------------- GEMM (R9): C = A @ Bt^T, bf16 in, fp32 or bf16 out ---------
// 128x128 tile, 4 waves, BK=32. 2-phase double-buffered loop: STAGE(t+1)
// issued first, ds_read+MFMA on t, single barrier/iter. T2 slot-XOR swizzle.
template <int OUTBF>
__global__ __launch_bounds__(256) void gemm_bt_t(const unsigned short* __restrict__ A,
                                                 const unsigned short* __restrict__ Bt,
                                                 void* __restrict__ Cv,
                                                 int M, int N, int K) {
  __shared__ alignas(16) unsigned short sA[2][128][32];
  __shared__ alignas(16) unsigned short sB[2][128][32];
  const int tid = threadIdx.x;
  const int lane = tid & 63;
  const int w = tid >> 6;
  const int wm = (w >> 1) * 64, wn = (w & 1) * 64;
  const int nwg = gridDim.x * gridDim.y;
  int bid = blockIdx.y * gridDim.x + blockIdx.x;
  bid = (bid & 7) * (nwg >> 3) + (bid >> 3);
  const int m0 = (bid % gridDim.x) * 128, n0 = (bid / gridDim.x) * 128;
  const int l15 = lane & 15, lhi = lane >> 4;
  f32x4 acc[4][4];
#pragma unroll
  for (int i = 0; i < 4; ++i)
#pragma unroll
    for (int j = 0; j < 4; ++j) acc[i][j] = (f32x4){0.f, 0.f, 0.f, 0.f};
  const int row = tid >> 2;
  const int srcslot = (tid & 3) ^ ((row >> 1) & 3);
  const unsigned short* gA0 = A + (size_t)(m0 + row) * K + srcslot * 8;
  const unsigned short* gA1 = A + (size_t)(m0 + 64 + row) * K + srcslot * 8;
  const unsigned short* gB0 = Bt + (size_t)(n0 + row) * K + srcslot * 8;
  const unsigned short* gB1 = Bt + (size_t)(n0 + 64 + row) * K + srcslot * 8;
  char* ldsA = (char*)&sA[0][0][0] + w * 1024;   // wave-uniform; HW adds lane*16
  char* ldsB = (char*)&sB[0][0][0] + w * 1024;
  auto STAGE = [&](int bb, int k0) {
    GLD_LDS16(gA0 + k0, ldsA + bb * 8192);
    GLD_LDS16(gA1 + k0, ldsA + bb * 8192 + 4096);
    GLD_LDS16(gB0 + k0, ldsB + bb * 8192);
    GLD_LDS16(gB1 + k0, ldsB + bb * 8192 + 4096);
  };
  const int sphys = (lhi ^ ((l15 >> 1) & 3)) * 8;
  const int nt = K >> 5;
  STAGE(0, 0);
  __syncthreads();                       // drains vmcnt -> buf0 ready
  int cur = 0;
  for (int t = 0; t < nt; ++t) {
    if (t + 1 < nt) STAGE(cur ^ 1, (t + 1) * 32);
    s16x8 af[4], bfr[4];
#pragma unroll
    for (int i = 0; i < 4; ++i) af[i] = *(const s16x8*)&sA[cur][wm + i * 16 + l15][sphys];
#pragma unroll
    for (int j = 0; j < 4; ++j) bfr[j] = *(const s16x8*)&sB[cur][wn + j * 16 + l15][sphys];
#pragma unroll
    for (int i = 0; i < 4; ++i)
#pragma unroll
      for (int j = 0; j < 4; ++j)
        acc[i][j] = __builtin_amdgcn_mfma_f32_16x16x32_bf16(af[i], bfr[j], acc[i][j], 0, 0, 0);
    __syncthreads();                     // drains vmcnt(0): next buf landed
    cur ^= 1;
  }
  const int col0 = n0 + wn + l15;
  const int row00 = m0 + wm + lhi * 4;
  if (OUTBF) {
    unsigned short* C = (unsigned short*)Cv;
#pragma unroll
    for (int i = 0; i < 4; ++i)
#pragma unroll
      for (int j = 0; j < 4; ++j)
#pragma unroll
        for (int r = 0; r < 4; ++r)
          C[(size_t)(row00 + i * 16 + r) * N + col0 + j * 16] = f2bf(acc[i][j][r]);
  } else {
    float* C = (float*)Cv;
#pragma unroll
    for (int i = 0; i < 4; ++i)
#pragma unroll
      for (int j = 0; j < 4; ++j)
#pragma unroll
        for (int r = 0; r < 4; ++r)
          C[(size_t)(row00 + i * 16 + r) * N + col0 + j * 16] = acc[i][j][r];
  }
}

// ---------------- prep2: normrope | vtrans -----------------------------------
// block ranges: [0,20480) normrope, [20480,20992) vtrans
__global__ __launch_bounds__(256) void prep2_k(const unsigned short* __restrict__ qkvb,
                                               const float* __restrict__ qw,
                                               const float* __restrict__ kw,
                                               const float2* __restrict__ cstab,
                                               unsigned short* __restrict__ qT,
                                               unsigned short* __restrict__ kT,
                                               unsigned short* __restrict__ vT) {
  __shared__ unsigned short lt[64][65];
  const int bid = blockIdx.x;
  if (bid < 20480) {                       // RMSNorm + RoPE + pack
    constexpr float FOLD =
        (float)(1.4426950408889634 / ((0.1 * 0.6931471805599453 + 1.0) * 11.313708498984761));
    int wid = bid * 4 + (threadIdx.x >> 6);
    int lane = threadIdx.x & 63;
    const unsigned short* src; const float* wgt; unsigned short* dst;
    int t; float fold;
    if (wid < 65536) {
      int bt = wid >> 4, h = wid & 15;
      int b = bt >> 11; t = bt & 2047;
      src = qkvb + (size_t)bt * 3072 + h * 128;
      wgt = qw;
      dst = qT + ((size_t)(b * 16 + h) * 2048 + t) * 128;
      fold = FOLD;
    } else {
      int id = wid - 65536;
      int bt = id >> 2, g = id & 3;
      int b = bt >> 11; t = bt & 2047;
      src = qkvb + (size_t)bt * 3072 + 2048 + g * 128;
      wgt = kw;
      dst = kT + ((size_t)(b * 4 + g) * 2048 + t) * 128;
      fold = 1.0f;
    }
    unsigned int vv = ((const unsigned int*)src)[lane];   // 2 bf16
    float vx = bf2f((unsigned short)(vv & 0xffff));
    float vy = bf2f((unsigned short)(vv >> 16));
    float ss = vx * vx + vy * vy;
#pragma unroll
    for (int m = 32; m; m >>= 1) ss += __shfl_xor(ss, m);
    float rs = rsqrtf(ss * (1.0f / 128.0f) + 1.1920929e-07f);
    float2 wv = ((const float2*)wgt)[lane];
    float xn0 = vx * rs * wv.x;
    float xn1 = vy * rs * wv.y;
    float px = __shfl_xor(xn0, 32);
    float py = __shfl_xor(xn1, 32);
    float sgn = (lane < 32) ? -1.0f : 1.0f;
    int f0 = (2 * lane) & 63;
    float4 cs = ((const float4*)cstab)[((size_t)t * 64 + f0) >> 1];
    float r0 = (xn0 * cs.x + sgn * px * cs.y) * fold;
    float r1 = (xn1 * cs.z + sgn * py * cs.w) * fold;
    unsigned int packed = (unsigned int)f2bf(r0) | ((unsigned int)f2bf(r1) << 16);
    ((unsigned int*)dst)[lane] = packed;
  } else {                                 // v -> vT[b,g,d,t'] (t' pi-permuted)
    int b2 = bid - 20480;
    const int tt0 = (b2 & 31) * 64;
    const int dd0 = ((b2 >> 5) & 1) * 64;
    const int z = b2 >> 6;
    const int b = z >> 2, g = z & 3;
    const int j = threadIdx.x & 63, i4 = threadIdx.x >> 6;
    const unsigned short* src = qkvb + (size_t)b * 2048 * 3072 + 2560 + g * 128 + dd0;
#pragma unroll
    for (int p = 0; p < 16; ++p) {
      int i = p * 4 + i4;
      lt[i][j] = src[(size_t)(tt0 + i) * 3072 + j];
    }
    __syncthreads();
    unsigned short* dst = vT + ((size_t)(b * 4 + g) * 128 + dd0) * 2048 + tt0;
    const int jp = (j & 32) | (((j & 15) >> 2) << 3) | (((j >> 4) & 1) << 2) | (j & 3);
#pragma unroll
    for (int p = 0; p < 16; ++p) {
      int d = p * 4 + i4;
      dst[(size_t)d * 2048 + jp] = lt[j][d];
    }
  }
}

// ---------------- causal flash attention (R9 version, reverted) --------------
// 4 waves x 16 q-rows; swapped QK^T; reg->LDS staging; grid 1024 with
// bid%8 = b*4+g (XCD pin), qt = 31-(bid>>5) (heavy first).
__global__ __launch_bounds__(256) void attn_k(const unsigned short* __restrict__ qT,
                                              const unsigned short* __restrict__ kT,
                                              const unsigned short* __restrict__ vT,
                                              unsigned short* __restrict__ ao) {
  __shared__ alignas(16) unsigned short sK[64][136];
  __shared__ alignas(16) unsigned short sVt[128][72];
  const int tid = threadIdx.x;
  const int lane = tid & 63;
  const int w = tid >> 6;
  const int l15 = lane & 15, lhi = lane >> 4;
  const int bid = blockIdx.x;              // 0..1023
  const int xg = bid & 7;                  // b*4+g
  const int b = xg >> 2, g = xg & 3;
  const int hh = (bid >> 3) & 3;
  const int h = hh * 4 + g;                // g == h&3
  const int qt = 31 - (bid >> 5);          // heavy first
  const int q0 = qt * 64;
  const unsigned short* Qb = qT + ((size_t)(b * 16 + h) * 2048) * 128;
  const unsigned short* Kb = kT + ((size_t)(b * 4 + g) * 2048) * 128;
  const unsigned short* Vb = vT + ((size_t)(b * 4 + g) * 128) * 2048;
  const int kr = tid >> 4, kc = (tid & 15) * 8;
  const int vr = tid >> 3, vc = (tid & 7) * 8;

  s16x8 qfr[4];
#pragma unroll
  for (int ks = 0; ks < 4; ++ks)
    qfr[ks] = *(const s16x8*)(Qb + (size_t)(q0 + w * 16 + l15) * 128 + ks * 32 + lhi * 8);

  u32x4 gk[4], gv[4];
#pragma unroll
  for (int p = 0; p < 4; ++p) {
    gk[p] = *(const u32x4*)(Kb + (size_t)(p * 16 + kr) * 128 + kc);
    gv[p] = *(const u32x4*)(Vb + (size_t)(p * 32 + vr) * 2048 + vc);
  }
  f32x4 o[8];
#pragma unroll
  for (int i = 0; i < 8; ++i) o[i] = (f32x4){0.f, 0.f, 0.f, 0.f};
  f32x4 o9 = (f32x4){0.f, 0.f, 0.f, 0.f};   // row sums via ones-MFMA
  float m_run = -INFINITY;
  s16x8 ones;
#pragma unroll
  for (int j = 0; j < 8; ++j) ones[j] = (short)0x3F80;  // bf16 1.0

  for (int kt = 0; kt <= qt; ++kt) {
    __syncthreads();
#pragma unroll
    for (int p = 0; p < 4; ++p) {
      *(u32x4*)&sK[p * 16 + kr][kc] = gk[p];
      *(u32x4*)&sVt[p * 32 + vr][vc] = gv[p];
    }
    __syncthreads();
    if (kt < qt) {                         // T14: issue next-tile loads early
#pragma unroll
      for (int p = 0; p < 4; ++p) {
        gk[p] = *(const u32x4*)(Kb + (size_t)((kt + 1) * 64 + p * 16 + kr) * 128 + kc);
        gv[p] = *(const u32x4*)(Vb + (size_t)(p * 32 + vr) * 2048 + (kt + 1) * 64 + vc);
      }
    }
    f32x4 s[4];
#pragma unroll
    for (int jn = 0; jn < 4; ++jn) s[jn] = (f32x4){0.f, 0.f, 0.f, 0.f};
#pragma unroll
    for (int ks = 0; ks < 4; ++ks)
#pragma unroll
      for (int jn = 0; jn < 4; ++jn) {
        s16x8 ak = *(const s16x8*)&sK[jn * 16 + l15][ks * 32 + lhi * 8];
        s[jn] = __builtin_amdgcn_mfma_f32_16x16x32_bf16(ak, qfr[ks], s[jn], 0, 0, 0);
      }
    if (kt == qt) {
#pragma unroll
      for (int jn = 0; jn < 4; ++jn)
#pragma unroll
        for (int r = 0; r < 4; ++r)
          if (jn * 16 + lhi * 4 + r > w * 16 + l15) s[jn][r] = -INFINITY;
    }
    float mx = fmaxf(fmaxf(fmaxf(s[0][0], s[0][1]), fmaxf(s[0][2], s[0][3])),
                     fmaxf(fmaxf(s[1][0], s[1][1]), fmaxf(s[1][2], s[1][3])));
    mx = fmaxf(mx, fmaxf(fmaxf(fmaxf(s[2][0], s[2][1]), fmaxf(s[2][2], s[2][3])),
                         fmaxf(fmaxf(s[3][0], s[3][1]), fmaxf(s[3][2], s[3][3]))));
    mx = fmaxf(mx, __shfl_xor(mx, 16));
    mx = fmaxf(mx, __shfl_xor(mx, 32));
    if (!__all(mx - m_run <= 8.0f)) {      // T13 defer-max
      float mnew = fmaxf(m_run, mx);
      float scale = exp2f(m_run - mnew);
      m_run = mnew;
      float sc_o[4];
#pragma unroll
      for (int r = 0; r < 4; ++r) sc_o[r] = __shfl(scale, lhi * 4 + r);
#pragma unroll
      for (int nt = 0; nt < 8; ++nt)
#pragma unroll
        for (int r = 0; r < 4; ++r) o[nt][r] *= sc_o[r];
#pragma unroll
      for (int r = 0; r < 4; ++r) o9[r] *= sc_o[r];
    }
    float pp[4][4];
#pragma unroll
    for (int jn = 0; jn < 4; ++jn)
#pragma unroll
      for (int r = 0; r < 4; ++r) pp[jn][r] = exp2f(s[jn][r] - m_run);
    union { s16x8 v; unsigned int d[4]; } pa0, pa1;
#pragma unroll
    for (int d = 0; d < 2; ++d) {
      pa0.d[d]     = cvt_pk_bf16(pp[0][2 * d], pp[0][2 * d + 1]);
      pa0.d[2 + d] = cvt_pk_bf16(pp[1][2 * d], pp[1][2 * d + 1]);
      pa1.d[d]     = cvt_pk_bf16(pp[2][2 * d], pp[2][2 * d + 1]);
      pa1.d[2 + d] = cvt_pk_bf16(pp[3][2 * d], pp[3][2 * d + 1]);
    }
    o9 = __builtin_amdgcn_mfma_f32_16x16x32_bf16(pa0.v, ones, o9, 0, 0, 0);
    o9 = __builtin_amdgcn_mfma_f32_16x16x32_bf16(pa1.v, ones, o9, 0, 0, 0);
#pragma unroll
    for (int nt = 0; nt < 8; ++nt) {
      s16x8 vb0 = *(const s16x8*)&sVt[nt * 16 + l15][lhi * 8];
      o[nt] = __builtin_amdgcn_mfma_f32_16x16x32_bf16(pa0.v, vb0, o[nt], 0, 0, 0);
    }
#pragma unroll
    for (int nt = 0; nt < 8; ++nt) {
      s16x8 vb1 = *(const s16x8*)&sVt[nt * 16 + l15][32 + lhi * 8];
      o[nt] = __builtin_amdgcn_mfma_f32_16x16x32_bf16(pa1.v, vb1, o[nt], 0, 0, 0);
    }
  }
#pragma unroll
  for (int r = 0; r < 4; ++r) {
    float invr = 1.0f / o9[r];
    int t = q0 + w * 16 + lhi * 4 + r;
    size_t base = ((size_t)b * 2048 + t) * 2048 + h * 128;
#pragma unroll
    for (int nt = 0; nt < 8; ++nt)
      ao[base + nt * 16 + l15] = f2bf(o[nt][r] * invr);
  }
}

// ---------------------------------------------------------------------------
extern "C" void kernel_launch(void* const* d_in, const int* in_sizes, int n_in,
                              void* d_out, int out_size, void* d_ws, size_t ws_size,
                              hipStream_t stream) {
  (void)in_sizes; (void)n_in; (void)out_size; (void)ws_size;
  const float* x    = (const float*)d_in[0];
  const float* Wq   = (const float*)d_in[1];
  const float* Wkv  = (const float*)d_in[2];
  const float* Wout = (const float*)d_in[3];
  const float* qw   = (const float*)d_in[4];
  const float* kw   = (const float*)d_in[5];
  const float* invf = (const float*)d_in[6];
  float* out = (float*)d_out;

  char* ws = (char*)d_ws;
  size_t off = 0;
  auto alloc = [&](size_t bytes) -> void* {
    void* p = ws + off; off += (bytes + 255) & ~(size_t)255; return p;
  };
  unsigned short* xb    = (unsigned short*)alloc((size_t)4096 * 2048 * 2);
  unsigned short* wqkvt = (unsigned short*)alloc((size_t)3072 * 2048 * 2);
  unsigned short* wot   = (unsigned short*)alloc((size_t)2048 * 2048 * 2);
  unsigned short* qkvb  = (unsigned short*)alloc((size_t)4096 * 3072 * 2);
  float2* cstab = (float2*)alloc((size_t)2048 * 64 * 8);
  unsigned short* qT = (unsigned short*)alloc((size_t)2 * 16 * 2048 * 128 * 2);
  unsigned short* kT = (unsigned short*)alloc((size_t)2 * 4 * 2048 * 128 * 2);
  unsigned short* vT = (unsigned short*)alloc((size_t)2 * 4 * 128 * 2048 * 2);
  unsigned short* ao = (unsigned short*)alloc((size_t)4096 * 2048 * 2);

  prep1_k<<<11264, 256, 0, stream>>>(x, Wq, Wkv, Wout, invf, xb, wqkvt, wot, cstab);
  gemm_bt_t<1><<<dim3(32, 24), 256, 0, stream>>>(xb, wqkvt, qkvb, 4096, 3072, 2048);
  prep2_k<<<20992, 256, 0, stream>>>(qkvb, qw, kw, cstab, qT, kT, vT);
  attn_k<<<1024, 256, 0, stream>>>(qT, kT, vT, ao);
  gemm_bt_t<0><<<dim3(32, 16), 256, 0, stream>>>(ao, wot, out, 4096, 2048, 2048);
}

// Round 15
// 201.798 us; speedup vs baseline: 1.2301x; 1.0526x over previous
//
#include <hip/hip_runtime.h>
#include <math.h>

// ---------------------------------------------------------------------------
// Fused YaRN-GQA attention block, bf16 MFMA pipeline.
// R15: attn staging rebuilt — global_load_lds direct into linear double-
//      buffered LDS (64KB) with both-sides XOR slot swizzle (rule #21):
//      source slot pre-swizzled with ^(row&7), fragment reads apply the same
//      XOR. Removes all staging ds_writes (8-way conflicted, 8.65M/dispatch)
//      and the reg round-trip. 2-phase schedule: vmcnt(0) + 1 barrier/iter,
//      GLD(kt+1) issued right after the barrier. Rest frozen from R14.
// ---------------------------------------------------------------------------

typedef __attribute__((ext_vector_type(8))) short s16x8;
typedef __attribute__((ext_vector_type(4))) float f32x4;
typedef __attribute__((ext_vector_type(4))) unsigned int u32x4;

__device__ __forceinline__ unsigned short f2bf(float x) {
  union { float f; unsigned int u; } v; v.f = x;
  return (unsigned short)((v.u + 0x7FFFu + ((v.u >> 16) & 1u)) >> 16);
}

__device__ __forceinline__ float bf2f(unsigned short x) {
  union { unsigned int u; float f; } v; v.u = (unsigned int)x << 16;
  return v.f;
}

__device__ __forceinline__ unsigned int cvt_pk_bf16(float lo, float hi) {
  unsigned int r;
  asm("v_cvt_pk_bf16_f32 %0, %1, %2" : "=v"(r) : "v"(lo), "v"(hi));
  return r;
}

#define GLD_LDS16(g, l)                                            \
  __builtin_amdgcn_global_load_lds(                                \
      (const __attribute__((address_space(1))) void*)(g),          \
      (__attribute__((address_space(3))) void*)(l), 16, 0, 0)

// ---------------- prep1: cast x->bf16 | Wq^T | Wkv^T | Wout^T | trig --------
__device__ __forceinline__ void wtrans_body(const float* __restrict__ in,
                                            unsigned short* __restrict__ out,
                                            int R, int C, int bx, int by,
                                            unsigned short lt[64][65]) {
  const int r0 = bx * 64, c0 = by * 64;
  const int j = threadIdx.x & 63, i4 = threadIdx.x >> 6;
#pragma unroll
  for (int p = 0; p < 16; ++p) {
    int i = p * 4 + i4;
    lt[i][j] = f2bf(in[(size_t)(r0 + i) * C + c0 + j]);
  }
  __syncthreads();
#pragma unroll
  for (int p = 0; p < 16; ++p) {
    int i = p * 4 + i4;
    out[(size_t)(c0 + i) * R + r0 + j] = lt[j][i];
  }
}

__global__ __launch_bounds__(256) void prep1_k(const float* __restrict__ x,
                                               const float* __restrict__ Wq,
                                               const float* __restrict__ Wkv,
                                               const float* __restrict__ Wout,
                                               const float* __restrict__ invf,
                                               unsigned short* __restrict__ xb,
                                               unsigned short* __restrict__ wqkvt,
                                               unsigned short* __restrict__ wot,
                                               float2* __restrict__ cstab) {
  __shared__ unsigned short lt[64][65];
  const int bid = blockIdx.x;
  if (bid < 8192) {
    int i = bid * 256 + threadIdx.x;
    float4 v = ((const float4*)x)[i];
    unsigned long long pack = (unsigned long long)f2bf(v.x)
                            | ((unsigned long long)f2bf(v.y) << 16)
                            | ((unsigned long long)f2bf(v.z) << 32)
                            | ((unsigned long long)f2bf(v.w) << 48);
    ((unsigned long long*)xb)[i] = pack;
  } else if (bid < 9216) {
    int b2 = bid - 8192;
    wtrans_body(Wq, wqkvt, 2048, 2048, b2 & 31, b2 >> 5, lt);
  } else if (bid < 9728) {
    int b2 = bid - 9216;
    wtrans_body(Wkv, wqkvt + (size_t)2048 * 2048, 2048, 1024, b2 & 31, b2 >> 5, lt);
  } else if (bid < 10752) {
    int b2 = bid - 9728;
    wtrans_body(Wout, wot, 2048, 2048, b2 & 31, b2 >> 5, lt);
  } else {
    int i = (bid - 10752) * 256 + threadIdx.x;
    int t = i >> 6, f = i & 63;
    float s, c;
    sincosf((float)t * invf[f], &s, &c);
    cstab[i] = make_float2(c, s);
  }
}

// ---------------- GEMM (R9): C = A @ Bt^T, bf16 in, fp32 or bf16 out ---------
template <int OUTBF>
__global__ __launch_bounds__(256) void gemm_bt_t(const unsigned short* __restrict__ A,
                                                 const unsigned short* __restrict__ Bt,
                                                 void* __restrict__ Cv,
                                                 int M, int N, int K) {
  __shared__ alignas(16) unsigned short sA[2][128][32];
  __shared__ alignas(16) unsigned short sB[2][128][32];
  const int tid = threadIdx.x;
  const int lane = tid & 63;
  const int w = tid >> 6;
  const int wm = (w >> 1) * 64, wn = (w & 1) * 64;
  const int nwg = gridDim.x * gridDim.y;
  int bid = blockIdx.y * gridDim.x + blockIdx.x;
  bid = (bid & 7) * (nwg >> 3) + (bid >> 3);
  const int m0 = (bid % gridDim.x) * 128, n0 = (bid / gridDim.x) * 128;
  const int l15 = lane & 15, lhi = lane >> 4;
  f32x4 acc[4][4];
#pragma unroll
  for (int i = 0; i < 4; ++i)
#pragma unroll
    for (int j = 0; j < 4; ++j) acc[i][j] = (f32x4){0.f, 0.f, 0.f, 0.f};
  const int row = tid >> 2;
  const int srcslot = (tid & 3) ^ ((row >> 1) & 3);
  const unsigned short* gA0 = A + (size_t)(m0 + row) * K + srcslot * 8;
  const unsigned short* gA1 = A + (size_t)(m0 + 64 + row) * K + srcslot * 8;
  const unsigned short* gB0 = Bt + (size_t)(n0 + row) * K + srcslot * 8;
  const unsigned short* gB1 = Bt + (size_t)(n0 + 64 + row) * K + srcslot * 8;
  char* ldsA = (char*)&sA[0][0][0] + w * 1024;   // wave-uniform; HW adds lane*16
  char* ldsB = (char*)&sB[0][0][0] + w * 1024;
  auto STAGE = [&](int bb, int k0) {
    GLD_LDS16(gA0 + k0, ldsA + bb * 8192);
    GLD_LDS16(gA1 + k0, ldsA + bb * 8192 + 4096);
    GLD_LDS16(gB0 + k0, ldsB + bb * 8192);
    GLD_LDS16(gB1 + k0, ldsB + bb * 8192 + 4096);
  };
  const int sphys = (lhi ^ ((l15 >> 1) & 3)) * 8;
  const int nt = K >> 5;
  STAGE(0, 0);
  __syncthreads();                       // drains vmcnt -> buf0 ready
  int cur = 0;
  for (int t = 0; t < nt; ++t) {
    if (t + 1 < nt) STAGE(cur ^ 1, (t + 1) * 32);
    s16x8 af[4], bfr[4];
#pragma unroll
    for (int i = 0; i < 4; ++i) af[i] = *(const s16x8*)&sA[cur][wm + i * 16 + l15][sphys];
#pragma unroll
    for (int j = 0; j < 4; ++j) bfr[j] = *(const s16x8*)&sB[cur][wn + j * 16 + l15][sphys];
#pragma unroll
    for (int i = 0; i < 4; ++i)
#pragma unroll
      for (int j = 0; j < 4; ++j)
        acc[i][j] = __builtin_amdgcn_mfma_f32_16x16x32_bf16(af[i], bfr[j], acc[i][j], 0, 0, 0);
    __syncthreads();                     // drains vmcnt(0): next buf landed
    cur ^= 1;
  }
  const int col0 = n0 + wn + l15;
  const int row00 = m0 + wm + lhi * 4;
  if (OUTBF) {
    unsigned short* C = (unsigned short*)Cv;
#pragma unroll
    for (int i = 0; i < 4; ++i)
#pragma unroll
      for (int j = 0; j < 4; ++j)
#pragma unroll
        for (int r = 0; r < 4; ++r)
          C[(size_t)(row00 + i * 16 + r) * N + col0 + j * 16] = f2bf(acc[i][j][r]);
  } else {
    float* C = (float*)Cv;
#pragma unroll
    for (int i = 0; i < 4; ++i)
#pragma unroll
      for (int j = 0; j < 4; ++j)
#pragma unroll
        for (int r = 0; r < 4; ++r)
          C[(size_t)(row00 + i * 16 + r) * N + col0 + j * 16] = acc[i][j][r];
  }
}

// ---------------- prep2: normrope | vtrans -----------------------------------
__global__ __launch_bounds__(256) void prep2_k(const unsigned short* __restrict__ qkvb,
                                               const float* __restrict__ qw,
                                               const float* __restrict__ kw,
                                               const float2* __restrict__ cstab,
                                               unsigned short* __restrict__ qT,
                                               unsigned short* __restrict__ kT,
                                               unsigned short* __restrict__ vT) {
  __shared__ unsigned short lt[64][65];
  const int bid = blockIdx.x;
  if (bid < 20480) {
    constexpr float FOLD =
        (float)(1.4426950408889634 / ((0.1 * 0.6931471805599453 + 1.0) * 11.313708498984761));
    int wid = bid * 4 + (threadIdx.x >> 6);
    int lane = threadIdx.x & 63;
    const unsigned short* src; const float* wgt; unsigned short* dst;
    int t; float fold;
    if (wid < 65536) {
      int bt = wid >> 4, h = wid & 15;
      int b = bt >> 11; t = bt & 2047;
      src = qkvb + (size_t)bt * 3072 + h * 128;
      wgt = qw;
      dst = qT + ((size_t)(b * 16 + h) * 2048 + t) * 128;
      fold = FOLD;
    } else {
      int id = wid - 65536;
      int bt = id >> 2, g = id & 3;
      int b = bt >> 11; t = bt & 2047;
      src = qkvb + (size_t)bt * 3072 + 2048 + g * 128;
      wgt = kw;
      dst = kT + ((size_t)(b * 4 + g) * 2048 + t) * 128;
      fold = 1.0f;
    }
    unsigned int vv = ((const unsigned int*)src)[lane];
    float vx = bf2f((unsigned short)(vv & 0xffff));
    float vy = bf2f((unsigned short)(vv >> 16));
    float ss = vx * vx + vy * vy;
#pragma unroll
    for (int m = 32; m; m >>= 1) ss += __shfl_xor(ss, m);
    float rs = rsqrtf(ss * (1.0f / 128.0f) + 1.1920929e-07f);
    float2 wv = ((const float2*)wgt)[lane];
    float xn0 = vx * rs * wv.x;
    float xn1 = vy * rs * wv.y;
    float px = __shfl_xor(xn0, 32);
    float py = __shfl_xor(xn1, 32);
    float sgn = (lane < 32) ? -1.0f : 1.0f;
    int f0 = (2 * lane) & 63;
    float4 cs = ((const float4*)cstab)[((size_t)t * 64 + f0) >> 1];
    float r0 = (xn0 * cs.x + sgn * px * cs.y) * fold;
    float r1 = (xn1 * cs.z + sgn * py * cs.w) * fold;
    unsigned int packed = (unsigned int)f2bf(r0) | ((unsigned int)f2bf(r1) << 16);
    ((unsigned int*)dst)[lane] = packed;
  } else {
    int b2 = bid - 20480;
    const int tt0 = (b2 & 31) * 64;
    const int dd0 = ((b2 >> 5) & 1) * 64;
    const int z = b2 >> 6;
    const int b = z >> 2, g = z & 3;
    const int j = threadIdx.x & 63, i4 = threadIdx.x >> 6;
    const unsigned short* src = qkvb + (size_t)b * 2048 * 3072 + 2560 + g * 128 + dd0;
#pragma unroll
    for (int p = 0; p < 16; ++p) {
      int i = p * 4 + i4;
      lt[i][j] = src[(size_t)(tt0 + i) * 3072 + j];
    }
    __syncthreads();
    unsigned short* dst = vT + ((size_t)(b * 4 + g) * 128 + dd0) * 2048 + tt0;
    const int jp = (j & 32) | (((j & 15) >> 2) << 3) | (((j >> 4) & 1) << 2) | (j & 3);
#pragma unroll
    for (int p = 0; p < 16; ++p) {
      int d = p * 4 + i4;
      dst[(size_t)d * 2048 + jp] = lt[j][d];
    }
  }
}

// ---------------- causal flash attention (R15: GLD-direct staging) -----------
// 4 waves x 16 q-rows; swapped QK^T; K/V staged via global_load_lds into
// linear double-buffered LDS with both-sides XOR (slot ^ (row&7)).
// Grid 1024: bid%8 = b*4+g (XCD pin), qt = 31-(bid>>5) (heavy first).
__global__ __launch_bounds__(256) void attn_k(const unsigned short* __restrict__ qT,
                                              const unsigned short* __restrict__ kT,
                                              const unsigned short* __restrict__ vT,
                                              unsigned short* __restrict__ ao) {
  __shared__ alignas(16) unsigned short sK2[2][64][128];    // 32 KB
  __shared__ alignas(16) unsigned short sV2[2][128][64];    // 32 KB
  const int tid = threadIdx.x;
  const int lane = tid & 63;
  const int w = tid >> 6;
  const int l15 = lane & 15, lhi = lane >> 4;
  const int l8 = lane >> 3;
  const int bid = blockIdx.x;              // 0..1023
  const int xg = bid & 7;                  // b*4+g
  const int b = xg >> 2, g = xg & 3;
  const int hh = (bid >> 3) & 3;
  const int h = hh * 4 + g;                // g == h&3
  const int qt = 31 - (bid >> 5);          // heavy first
  const int q0 = qt * 64;
  const unsigned short* Qb = qT + ((size_t)(b * 16 + h) * 2048) * 128;
  const unsigned short* Kb = kT + ((size_t)(b * 4 + g) * 2048) * 128;
  const unsigned short* Vb = vT + ((size_t)(b * 4 + g) * 128) * 2048;

  // Q fragments direct from global (B-operand: col=l15 row, k=d slice)
  s16x8 qfr[4];
#pragma unroll
  for (int ks = 0; ks < 4; ++ks)
    qfr[ks] = *(const s16x8*)(Qb + (size_t)(q0 + w * 16 + l15) * 128 + ks * 32 + lhi * 8);

  // staging geometry (per lane): K row = p*16 + w*4 + lhi, slot l15;
  //                              V row = p*32 + w*8 + l8,  slot lane&7.
  // pre-swizzled source slot = slot ^ (row & 7)
  const int sgK = l15 ^ ((w * 4 + lhi) & 7);
  const int sgV = (lane & 7) ^ (l8 & 7);
  char* ldsK = (char*)&sK2[0][0][0] + w * 1024;   // wave-uniform; HW adds lane*16
  char* ldsV = (char*)&sV2[0][0][0] + w * 1024;
  auto STAGEKV = [&](int bb, int kt) {
#pragma unroll
    for (int p = 0; p < 4; ++p) {
      GLD_LDS16(Kb + (size_t)(kt * 64 + p * 16 + w * 4 + lhi) * 128 + sgK * 8,
                ldsK + bb * 16384 + p * 4096);
      GLD_LDS16(Vb + (size_t)(p * 32 + w * 8 + l8) * 2048 + kt * 64 + sgV * 8,
                ldsV + bb * 16384 + p * 4096);
    }
  };
  // fragment-read XOR (row & 7 == l15 & 7 for both K and V reads)
  const int xr = l15 & 7;

  f32x4 o[8];
#pragma unroll
  for (int i = 0; i < 8; ++i) o[i] = (f32x4){0.f, 0.f, 0.f, 0.f};
  f32x4 o9 = (f32x4){0.f, 0.f, 0.f, 0.f};   // row sums via ones-MFMA
  float m_run = -INFINITY;
  s16x8 ones;
#pragma unroll
  for (int j = 0; j < 8; ++j) ones[j] = (short)0x3F80;  // bf16 1.0

  STAGEKV(0, 0);
  int cur = 0;
  for (int kt = 0; kt <= qt; ++kt) {
    asm volatile("s_waitcnt vmcnt(0)" ::: "memory");  // own buf[cur] loads landed
    __syncthreads();                                  // everyone's landed; prev reads done
    if (kt < qt) STAGEKV(cur ^ 1, kt + 1);            // prefetch under compute
    // S^T: s[jn][r] = S[qrow = q0+w*16+l15][kpos = kt*64+jn*16+lhi*4+r]
    f32x4 s[4];
#pragma unroll
    for (int jn = 0; jn < 4; ++jn) s[jn] = (f32x4){0.f, 0.f, 0.f, 0.f};
#pragma unroll
    for (int ks = 0; ks < 4; ++ks)
#pragma unroll
      for (int jn = 0; jn < 4; ++jn) {
        s16x8 ak = *(const s16x8*)&sK2[cur][jn * 16 + l15][((ks * 4 + lhi) ^ xr) * 8];
        s[jn] = __builtin_amdgcn_mfma_f32_16x16x32_bf16(ak, qfr[ks], s[jn], 0, 0, 0);
      }
    if (kt == qt) {                      // diagonal tile causal mask
#pragma unroll
      for (int jn = 0; jn < 4; ++jn)
#pragma unroll
        for (int r = 0; r < 4; ++r)
          if (jn * 16 + lhi * 4 + r > w * 16 + l15) s[jn][r] = -INFINITY;
    }
    float mx = fmaxf(fmaxf(fmaxf(s[0][0], s[0][1]), fmaxf(s[0][2], s[0][3])),
                     fmaxf(fmaxf(s[1][0], s[1][1]), fmaxf(s[1][2], s[1][3])));
    mx = fmaxf(mx, fmaxf(fmaxf(fmaxf(s[2][0], s[2][1]), fmaxf(s[2][2], s[2][3])),
                         fmaxf(fmaxf(s[3][0], s[3][1]), fmaxf(s[3][2], s[3][3]))));
    mx = fmaxf(mx, __shfl_xor(mx, 16));
    mx = fmaxf(mx, __shfl_xor(mx, 32));
    if (!__all(mx - m_run <= 8.0f)) {    // T13 defer-max
      float mnew = fmaxf(m_run, mx);
      float scale = exp2f(m_run - mnew);
      m_run = mnew;
      float sc_o[4];
#pragma unroll
      for (int r = 0; r < 4; ++r) sc_o[r] = __shfl(scale, lhi * 4 + r);
#pragma unroll
      for (int nt = 0; nt < 8; ++nt)
#pragma unroll
        for (int r = 0; r < 4; ++r) o[nt][r] *= sc_o[r];
#pragma unroll
      for (int r = 0; r < 4; ++r) o9[r] *= sc_o[r];
    }
    float pp[4][4];
#pragma unroll
    for (int jn = 0; jn < 4; ++jn)
#pragma unroll
      for (int r = 0; r < 4; ++r) pp[jn][r] = exp2f(s[jn][r] - m_run);
    union { s16x8 v; unsigned int d[4]; } pa0, pa1;
#pragma unroll
    for (int d = 0; d < 2; ++d) {
      pa0.d[d]     = cvt_pk_bf16(pp[0][2 * d], pp[0][2 * d + 1]);
      pa0.d[2 + d] = cvt_pk_bf16(pp[1][2 * d], pp[1][2 * d + 1]);
      pa1.d[d]     = cvt_pk_bf16(pp[2][2 * d], pp[2][2 * d + 1]);
      pa1.d[2 + d] = cvt_pk_bf16(pp[3][2 * d], pp[3][2 * d + 1]);
    }
    o9 = __builtin_amdgcn_mfma_f32_16x16x32_bf16(pa0.v, ones, o9, 0, 0, 0);
    o9 = __builtin_amdgcn_mfma_f32_16x16x32_bf16(pa1.v, ones, o9, 0, 0, 0);
    // O += P V   (V reads: logical slot lhi + ks2*4, XOR'd)
#pragma unroll
    for (int nt = 0; nt < 8; ++nt) {
      s16x8 vb0 = *(const s16x8*)&sV2[cur][nt * 16 + l15][(lhi ^ xr) * 8];
      o[nt] = __builtin_amdgcn_mfma_f32_16x16x32_bf16(pa0.v, vb0, o[nt], 0, 0, 0);
    }
#pragma unroll
    for (int nt = 0; nt < 8; ++nt) {
      s16x8 vb1 = *(const s16x8*)&sV2[cur][nt * 16 + l15][((lhi + 4) ^ xr) * 8];
      o[nt] = __builtin_amdgcn_mfma_f32_16x16x32_bf16(pa1.v, vb1, o[nt], 0, 0, 0);
    }
    cur ^= 1;
  }
#pragma unroll
  for (int r = 0; r < 4; ++r) {
    float invr = 1.0f / o9[r];
    int t = q0 + w * 16 + lhi * 4 + r;
    size_t base = ((size_t)b * 2048 + t) * 2048 + h * 128;
#pragma unroll
    for (int nt = 0; nt < 8; ++nt)
      ao[base + nt * 16 + l15] = f2bf(o[nt][r] * invr);
  }
}

// ---------------------------------------------------------------------------
extern "C" void kernel_launch(void* const* d_in, const int* in_sizes, int n_in,
                              void* d_out, int out_size, void* d_ws, size_t ws_size,
                              hipStream_t stream) {
  (void)in_sizes; (void)n_in; (void)out_size; (void)ws_size;
  const float* x    = (const float*)d_in[0];
  const float* Wq   = (const float*)d_in[1];
  const float* Wkv  = (const float*)d_in[2];
  const float* Wout = (const float*)d_in[3];
  const float* qw   = (const float*)d_in[4];
  const float* kw   = (const float*)d_in[5];
  const float* invf = (const float*)d_in[6];
  float* out = (float*)d_out;

  char* ws = (char*)d_ws;
  size_t off = 0;
  auto alloc = [&](size_t bytes) -> void* {
    void* p = ws + off; off += (bytes + 255) & ~(size_t)255; return p;
  };
  unsigned short* xb    = (unsigned short*)alloc((size_t)4096 * 2048 * 2);
  unsigned short* wqkvt = (unsigned short*)alloc((size_t)3072 * 2048 * 2);
  unsigned short* wot   = (unsigned short*)alloc((size_t)2048 * 2048 * 2);
  unsigned short* qkvb  = (unsigned short*)alloc((size_t)4096 * 3072 * 2);
  float2* cstab = (float2*)alloc((size_t)2048 * 64 * 8);
  unsigned short* qT = (unsigned short*)alloc((size_t)2 * 16 * 2048 * 128 * 2);
  unsigned short* kT = (unsigned short*)alloc((size_t)2 * 4 * 2048 * 128 * 2);
  unsigned short* vT = (unsigned short*)alloc((size_t)2 * 4 * 128 * 2048 * 2);
  unsigned short* ao = (unsigned short*)alloc((size_t)4096 * 2048 * 2);

  prep1_k<<<11264, 256, 0, stream>>>(x, Wq, Wkv, Wout, invf, xb, wqkvt, wot, cstab);
  gemm_bt_t<1><<<dim3(32, 24), 256, 0, stream>>>(xb, wqkvt, qkvb, 4096, 3072, 2048);
  prep2_k<<<20992, 256, 0, stream>>>(qkvb, qw, kw, cstab, qT, kT, vT);
  attn_k<<<1024, 256, 0, stream>>>(qT, kT, vT, ao);
  gemm_bt_t<0><<<dim3(32, 16), 256, 0, stream>>>(ao, wot, out, 4096, 2048, 2048);
}

// Round 16
// 193.604 us; speedup vs baseline: 1.2822x; 1.0423x over previous
//
#include <hip/hip_runtime.h>
#include <math.h>

// ---------------------------------------------------------------------------
// Fused YaRN-GQA attention block, bf16 MFMA pipeline.
// R16: attn softmax simplified to FIXED-MAX form. RMSNorm bounds |q.k| <= 128
//      => exp2-unit scores bounded by +-15.3 < 16, so P = exp2(s - 16) needs
//      no max tracking: the -16 is baked into the MFMA C-init, P = exp2(s).
//      Deletes fmax chain, shfl reduces, subs, defer-max/rescale (~45% of
//      softmax VALU). o and o9 both carry 2^-16 -> cancels in o/o9.
//      Rest frozen from R15 (GLD-direct staging, both-sides XOR, 2-phase).
// ---------------------------------------------------------------------------

typedef __attribute__((ext_vector_type(8))) short s16x8;
typedef __attribute__((ext_vector_type(4))) float f32x4;
typedef __attribute__((ext_vector_type(4))) unsigned int u32x4;

__device__ __forceinline__ unsigned short f2bf(float x) {
  union { float f; unsigned int u; } v; v.f = x;
  return (unsigned short)((v.u + 0x7FFFu + ((v.u >> 16) & 1u)) >> 16);
}

__device__ __forceinline__ float bf2f(unsigned short x) {
  union { unsigned int u; float f; } v; v.u = (unsigned int)x << 16;
  return v.f;
}

__device__ __forceinline__ unsigned int cvt_pk_bf16(float lo, float hi) {
  unsigned int r;
  asm("v_cvt_pk_bf16_f32 %0, %1, %2" : "=v"(r) : "v"(lo), "v"(hi));
  return r;
}

#define GLD_LDS16(g, l)                                            \
  __builtin_amdgcn_global_load_lds(                                \
      (const __attribute__((address_space(1))) void*)(g),          \
      (__attribute__((address_space(3))) void*)(l), 16, 0, 0)

// ---------------- prep1: cast x->bf16 | Wq^T | Wkv^T | Wout^T | trig --------
__device__ __forceinline__ void wtrans_body(const float* __restrict__ in,
                                            unsigned short* __restrict__ out,
                                            int R, int C, int bx, int by,
                                            unsigned short lt[64][65]) {
  const int r0 = bx * 64, c0 = by * 64;
  const int j = threadIdx.x & 63, i4 = threadIdx.x >> 6;
#pragma unroll
  for (int p = 0; p < 16; ++p) {
    int i = p * 4 + i4;
    lt[i][j] = f2bf(in[(size_t)(r0 + i) * C + c0 + j]);
  }
  __syncthreads();
#pragma unroll
  for (int p = 0; p < 16; ++p) {
    int i = p * 4 + i4;
    out[(size_t)(c0 + i) * R + r0 + j] = lt[j][i];
  }
}

__global__ __launch_bounds__(256) void prep1_k(const float* __restrict__ x,
                                               const float* __restrict__ Wq,
                                               const float* __restrict__ Wkv,
                                               const float* __restrict__ Wout,
                                               const float* __restrict__ invf,
                                               unsigned short* __restrict__ xb,
                                               unsigned short* __restrict__ wqkvt,
                                               unsigned short* __restrict__ wot,
                                               float2* __restrict__ cstab) {
  __shared__ unsigned short lt[64][65];
  const int bid = blockIdx.x;
  if (bid < 8192) {
    int i = bid * 256 + threadIdx.x;
    float4 v = ((const float4*)x)[i];
    unsigned long long pack = (unsigned long long)f2bf(v.x)
                            | ((unsigned long long)f2bf(v.y) << 16)
                            | ((unsigned long long)f2bf(v.z) << 32)
                            | ((unsigned long long)f2bf(v.w) << 48);
    ((unsigned long long*)xb)[i] = pack;
  } else if (bid < 9216) {
    int b2 = bid - 8192;
    wtrans_body(Wq, wqkvt, 2048, 2048, b2 & 31, b2 >> 5, lt);
  } else if (bid < 9728) {
    int b2 = bid - 9216;
    wtrans_body(Wkv, wqkvt + (size_t)2048 * 2048, 2048, 1024, b2 & 31, b2 >> 5, lt);
  } else if (bid < 10752) {
    int b2 = bid - 9728;
    wtrans_body(Wout, wot, 2048, 2048, b2 & 31, b2 >> 5, lt);
  } else {
    int i = (bid - 10752) * 256 + threadIdx.x;
    int t = i >> 6, f = i & 63;
    float s, c;
    sincosf((float)t * invf[f], &s, &c);
    cstab[i] = make_float2(c, s);
  }
}

// ---------------- GEMM (R9): C = A @ Bt^T, bf16 in, fp32 or bf16 out ---------
template <int OUTBF>
__global__ __launch_bounds__(256) void gemm_bt_t(const unsigned short* __restrict__ A,
                                                 const unsigned short* __restrict__ Bt,
                                                 void* __restrict__ Cv,
                                                 int M, int N, int K) {
  __shared__ alignas(16) unsigned short sA[2][128][32];
  __shared__ alignas(16) unsigned short sB[2][128][32];
  const int tid = threadIdx.x;
  const int lane = tid & 63;
  const int w = tid >> 6;
  const int wm = (w >> 1) * 64, wn = (w & 1) * 64;
  const int nwg = gridDim.x * gridDim.y;
  int bid = blockIdx.y * gridDim.x + blockIdx.x;
  bid = (bid & 7) * (nwg >> 3) + (bid >> 3);
  const int m0 = (bid % gridDim.x) * 128, n0 = (bid / gridDim.x) * 128;
  const int l15 = lane & 15, lhi = lane >> 4;
  f32x4 acc[4][4];
#pragma unroll
  for (int i = 0; i < 4; ++i)
#pragma unroll
    for (int j = 0; j < 4; ++j) acc[i][j] = (f32x4){0.f, 0.f, 0.f, 0.f};
  const int row = tid >> 2;
  const int srcslot = (tid & 3) ^ ((row >> 1) & 3);
  const unsigned short* gA0 = A + (size_t)(m0 + row) * K + srcslot * 8;
  const unsigned short* gA1 = A + (size_t)(m0 + 64 + row) * K + srcslot * 8;
  const unsigned short* gB0 = Bt + (size_t)(n0 + row) * K + srcslot * 8;
  const unsigned short* gB1 = Bt + (size_t)(n0 + 64 + row) * K + srcslot * 8;
  char* ldsA = (char*)&sA[0][0][0] + w * 1024;   // wave-uniform; HW adds lane*16
  char* ldsB = (char*)&sB[0][0][0] + w * 1024;
  auto STAGE = [&](int bb, int k0) {
    GLD_LDS16(gA0 + k0, ldsA + bb * 8192);
    GLD_LDS16(gA1 + k0, ldsA + bb * 8192 + 4096);
    GLD_LDS16(gB0 + k0, ldsB + bb * 8192);
    GLD_LDS16(gB1 + k0, ldsB + bb * 8192 + 4096);
  };
  const int sphys = (lhi ^ ((l15 >> 1) & 3)) * 8;
  const int nt = K >> 5;
  STAGE(0, 0);
  __syncthreads();                       // drains vmcnt -> buf0 ready
  int cur = 0;
  for (int t = 0; t < nt; ++t) {
    if (t + 1 < nt) STAGE(cur ^ 1, (t + 1) * 32);
    s16x8 af[4], bfr[4];
#pragma unroll
    for (int i = 0; i < 4; ++i) af[i] = *(const s16x8*)&sA[cur][wm + i * 16 + l15][sphys];
#pragma unroll
    for (int j = 0; j < 4; ++j) bfr[j] = *(const s16x8*)&sB[cur][wn + j * 16 + l15][sphys];
#pragma unroll
    for (int i = 0; i < 4; ++i)
#pragma unroll
      for (int j = 0; j < 4; ++j)
        acc[i][j] = __builtin_amdgcn_mfma_f32_16x16x32_bf16(af[i], bfr[j], acc[i][j], 0, 0, 0);
    __syncthreads();                     // drains vmcnt(0): next buf landed
    cur ^= 1;
  }
  const int col0 = n0 + wn + l15;
  const int row00 = m0 + wm + lhi * 4;
  if (OUTBF) {
    unsigned short* C = (unsigned short*)Cv;
#pragma unroll
    for (int i = 0; i < 4; ++i)
#pragma unroll
      for (int j = 0; j < 4; ++j)
#pragma unroll
        for (int r = 0; r < 4; ++r)
          C[(size_t)(row00 + i * 16 + r) * N + col0 + j * 16] = f2bf(acc[i][j][r]);
  } else {
    float* C = (float*)Cv;
#pragma unroll
    for (int i = 0; i < 4; ++i)
#pragma unroll
      for (int j = 0; j < 4; ++j)
#pragma unroll
        for (int r = 0; r < 4; ++r)
          C[(size_t)(row00 + i * 16 + r) * N + col0 + j * 16] = acc[i][j][r];
  }
}

// ---------------- prep2: normrope | vtrans -----------------------------------
__global__ __launch_bounds__(256) void prep2_k(const unsigned short* __restrict__ qkvb,
                                               const float* __restrict__ qw,
                                               const float* __restrict__ kw,
                                               const float2* __restrict__ cstab,
                                               unsigned short* __restrict__ qT,
                                               unsigned short* __restrict__ kT,
                                               unsigned short* __restrict__ vT) {
  __shared__ unsigned short lt[64][65];
  const int bid = blockIdx.x;
  if (bid < 20480) {
    constexpr float FOLD =
        (float)(1.4426950408889634 / ((0.1 * 0.6931471805599453 + 1.0) * 11.313708498984761));
    int wid = bid * 4 + (threadIdx.x >> 6);
    int lane = threadIdx.x & 63;
    const unsigned short* src; const float* wgt; unsigned short* dst;
    int t; float fold;
    if (wid < 65536) {
      int bt = wid >> 4, h = wid & 15;
      int b = bt >> 11; t = bt & 2047;
      src = qkvb + (size_t)bt * 3072 + h * 128;
      wgt = qw;
      dst = qT + ((size_t)(b * 16 + h) * 2048 + t) * 128;
      fold = FOLD;
    } else {
      int id = wid - 65536;
      int bt = id >> 2, g = id & 3;
      int b = bt >> 11; t = bt & 2047;
      src = qkvb + (size_t)bt * 3072 + 2048 + g * 128;
      wgt = kw;
      dst = kT + ((size_t)(b * 4 + g) * 2048 + t) * 128;
      fold = 1.0f;
    }
    unsigned int vv = ((const unsigned int*)src)[lane];
    float vx = bf2f((unsigned short)(vv & 0xffff));
    float vy = bf2f((unsigned short)(vv >> 16));
    float ss = vx * vx + vy * vy;
#pragma unroll
    for (int m = 32; m; m >>= 1) ss += __shfl_xor(ss, m);
    float rs = rsqrtf(ss * (1.0f / 128.0f) + 1.1920929e-07f);
    float2 wv = ((const float2*)wgt)[lane];
    float xn0 = vx * rs * wv.x;
    float xn1 = vy * rs * wv.y;
    float px = __shfl_xor(xn0, 32);
    float py = __shfl_xor(xn1, 32);
    float sgn = (lane < 32) ? -1.0f : 1.0f;
    int f0 = (2 * lane) & 63;
    float4 cs = ((const float4*)cstab)[((size_t)t * 64 + f0) >> 1];
    float r0 = (xn0 * cs.x + sgn * px * cs.y) * fold;
    float r1 = (xn1 * cs.z + sgn * py * cs.w) * fold;
    unsigned int packed = (unsigned int)f2bf(r0) | ((unsigned int)f2bf(r1) << 16);
    ((unsigned int*)dst)[lane] = packed;
  } else {
    int b2 = bid - 20480;
    const int tt0 = (b2 & 31) * 64;
    const int dd0 = ((b2 >> 5) & 1) * 64;
    const int z = b2 >> 6;
    const int b = z >> 2, g = z & 3;
    const int j = threadIdx.x & 63, i4 = threadIdx.x >> 6;
    const unsigned short* src = qkvb + (size_t)b * 2048 * 3072 + 2560 + g * 128 + dd0;
#pragma unroll
    for (int p = 0; p < 16; ++p) {
      int i = p * 4 + i4;
      lt[i][j] = src[(size_t)(tt0 + i) * 3072 + j];
    }
    __syncthreads();
    unsigned short* dst = vT + ((size_t)(b * 4 + g) * 128 + dd0) * 2048 + tt0;
    const int jp = (j & 32) | (((j & 15) >> 2) << 3) | (((j >> 4) & 1) << 2) | (j & 3);
#pragma unroll
    for (int p = 0; p < 16; ++p) {
      int d = p * 4 + i4;
      dst[(size_t)d * 2048 + jp] = lt[j][d];
    }
  }
}

// ---------------- causal flash attention (R16: fixed-max softmax) ------------
// 4 waves x 16 q-rows; swapped QK^T; GLD-direct staging (both-sides XOR).
// Scores bounded |s| <= 15.3 (RMSNorm) => P = exp2(s - 16) with -16 baked
// into the MFMA C-init; no max tracking, no rescale. o/o9 ratio cancels 2^-16.
__global__ __launch_bounds__(256) void attn_k(const unsigned short* __restrict__ qT,
                                              const unsigned short* __restrict__ kT,
                                              const unsigned short* __restrict__ vT,
                                              unsigned short* __restrict__ ao) {
  __shared__ alignas(16) unsigned short sK2[2][64][128];    // 32 KB
  __shared__ alignas(16) unsigned short sV2[2][128][64];    // 32 KB
  const int tid = threadIdx.x;
  const int lane = tid & 63;
  const int w = tid >> 6;
  const int l15 = lane & 15, lhi = lane >> 4;
  const int l8 = lane >> 3;
  const int bid = blockIdx.x;              // 0..1023
  const int xg = bid & 7;                  // b*4+g
  const int b = xg >> 2, g = xg & 3;
  const int hh = (bid >> 3) & 3;
  const int h = hh * 4 + g;                // g == h&3
  const int qt = 31 - (bid >> 5);          // heavy first
  const int q0 = qt * 64;
  const unsigned short* Qb = qT + ((size_t)(b * 16 + h) * 2048) * 128;
  const unsigned short* Kb = kT + ((size_t)(b * 4 + g) * 2048) * 128;
  const unsigned short* Vb = vT + ((size_t)(b * 4 + g) * 128) * 2048;

  // Q fragments direct from global (B-operand: col=l15 row, k=d slice)
  s16x8 qfr[4];
#pragma unroll
  for (int ks = 0; ks < 4; ++ks)
    qfr[ks] = *(const s16x8*)(Qb + (size_t)(q0 + w * 16 + l15) * 128 + ks * 32 + lhi * 8);

  // staging geometry (per lane): K row = p*16 + w*4 + lhi, slot l15;
  //                              V row = p*32 + w*8 + l8,  slot lane&7.
  const int sgK = l15 ^ ((w * 4 + lhi) & 7);
  const int sgV = (lane & 7) ^ (l8 & 7);
  char* ldsK = (char*)&sK2[0][0][0] + w * 1024;   // wave-uniform; HW adds lane*16
  char* ldsV = (char*)&sV2[0][0][0] + w * 1024;
  auto STAGEKV = [&](int bb, int kt) {
#pragma unroll
    for (int p = 0; p < 4; ++p) {
      GLD_LDS16(Kb + (size_t)(kt * 64 + p * 16 + w * 4 + lhi) * 128 + sgK * 8,
                ldsK + bb * 16384 + p * 4096);
      GLD_LDS16(Vb + (size_t)(p * 32 + w * 8 + l8) * 2048 + kt * 64 + sgV * 8,
                ldsV + bb * 16384 + p * 4096);
    }
  };
  const int xr = l15 & 7;                  // fragment-read XOR

  f32x4 o[8];
#pragma unroll
  for (int i = 0; i < 8; ++i) o[i] = (f32x4){0.f, 0.f, 0.f, 0.f};
  f32x4 o9 = (f32x4){0.f, 0.f, 0.f, 0.f};   // row sums via ones-MFMA
  s16x8 ones;
#pragma unroll
  for (int j = 0; j < 8; ++j) ones[j] = (short)0x3F80;  // bf16 1.0

  STAGEKV(0, 0);
  int cur = 0;
  for (int kt = 0; kt <= qt; ++kt) {
    asm volatile("s_waitcnt vmcnt(0)" ::: "memory");  // own buf[cur] loads landed
    __syncthreads();                                  // everyone's landed; prev reads done
    if (kt < qt) STAGEKV(cur ^ 1, kt + 1);            // prefetch under compute
    // S^T - 16: s[jn][r] = S[qrow][kpos] - 16 (C-init), exp2 units
    f32x4 s[4];
#pragma unroll
    for (int jn = 0; jn < 4; ++jn) s[jn] = (f32x4){-16.f, -16.f, -16.f, -16.f};
#pragma unroll
    for (int ks = 0; ks < 4; ++ks)
#pragma unroll
      for (int jn = 0; jn < 4; ++jn) {
        s16x8 ak = *(const s16x8*)&sK2[cur][jn * 16 + l15][((ks * 4 + lhi) ^ xr) * 8];
        s[jn] = __builtin_amdgcn_mfma_f32_16x16x32_bf16(ak, qfr[ks], s[jn], 0, 0, 0);
      }
    if (kt == qt) {                      // diagonal tile causal mask
#pragma unroll
      for (int jn = 0; jn < 4; ++jn)
#pragma unroll
        for (int r = 0; r < 4; ++r)
          if (jn * 16 + lhi * 4 + r > w * 16 + l15) s[jn][r] = -INFINITY;
    }
    // P = exp2(s) directly (fixed max; bounded (0, 1])
    float pp[4][4];
#pragma unroll
    for (int jn = 0; jn < 4; ++jn)
#pragma unroll
      for (int r = 0; r < 4; ++r) pp[jn][r] = exp2f(s[jn][r]);
    union { s16x8 v; unsigned int d[4]; } pa0, pa1;
#pragma unroll
    for (int d = 0; d < 2; ++d) {
      pa0.d[d]     = cvt_pk_bf16(pp[0][2 * d], pp[0][2 * d + 1]);
      pa0.d[2 + d] = cvt_pk_bf16(pp[1][2 * d], pp[1][2 * d + 1]);
      pa1.d[d]     = cvt_pk_bf16(pp[2][2 * d], pp[2][2 * d + 1]);
      pa1.d[2 + d] = cvt_pk_bf16(pp[3][2 * d], pp[3][2 * d + 1]);
    }
    o9 = __builtin_amdgcn_mfma_f32_16x16x32_bf16(pa0.v, ones, o9, 0, 0, 0);
    o9 = __builtin_amdgcn_mfma_f32_16x16x32_bf16(pa1.v, ones, o9, 0, 0, 0);
    // O += P V   (V reads: logical slot lhi (+4), XOR'd)
#pragma unroll
    for (int nt = 0; nt < 8; ++nt) {
      s16x8 vb0 = *(const s16x8*)&sV2[cur][nt * 16 + l15][(lhi ^ xr) * 8];
      o[nt] = __builtin_amdgcn_mfma_f32_16x16x32_bf16(pa0.v, vb0, o[nt], 0, 0, 0);
    }
#pragma unroll
    for (int nt = 0; nt < 8; ++nt) {
      s16x8 vb1 = *(const s16x8*)&sV2[cur][nt * 16 + l15][((lhi + 4) ^ xr) * 8];
      o[nt] = __builtin_amdgcn_mfma_f32_16x16x32_bf16(pa1.v, vb1, o[nt], 0, 0, 0);
    }
    cur ^= 1;
  }
#pragma unroll
  for (int r = 0; r < 4; ++r) {
    float invr = 1.0f / o9[r];
    int t = q0 + w * 16 + lhi * 4 + r;
    size_t base = ((size_t)b * 2048 + t) * 2048 + h * 128;
#pragma unroll
    for (int nt = 0; nt < 8; ++nt)
      ao[base + nt * 16 + l15] = f2bf(o[nt][r] * invr);
  }
}

// ---------------------------------------------------------------------------
extern "C" void kernel_launch(void* const* d_in, const int* in_sizes, int n_in,
                              void* d_out, int out_size, void* d_ws, size_t ws_size,
                              hipStream_t stream) {
  (void)in_sizes; (void)n_in; (void)out_size; (void)ws_size;
  const float* x    = (const float*)d_in[0];
  const float* Wq   = (const float*)d_in[1];
  const float* Wkv  = (const float*)d_in[2];
  const float* Wout = (const float*)d_in[3];
  const float* qw   = (const float*)d_in[4];
  const float* kw   = (const float*)d_in[5];
  const float* invf = (const float*)d_in[6];
  float* out = (float*)d_out;

  char* ws = (char*)d_ws;
  size_t off = 0;
  auto alloc = [&](size_t bytes) -> void* {
    void* p = ws + off; off += (bytes + 255) & ~(size_t)255; return p;
  };
  unsigned short* xb    = (unsigned short*)alloc((size_t)4096 * 2048 * 2);
  unsigned short* wqkvt = (unsigned short*)alloc((size_t)3072 * 2048 * 2);
  unsigned short* wot   = (unsigned short*)alloc((size_t)2048 * 2048 * 2);
  unsigned short* qkvb  = (unsigned short*)alloc((size_t)4096 * 3072 * 2);
  float2* cstab = (float2*)alloc((size_t)2048 * 64 * 8);
  unsigned short* qT = (unsigned short*)alloc((size_t)2 * 16 * 2048 * 128 * 2);
  unsigned short* kT = (unsigned short*)alloc((size_t)2 * 4 * 2048 * 128 * 2);
  unsigned short* vT = (unsigned short*)alloc((size_t)2 * 4 * 128 * 2048 * 2);
  unsigned short* ao = (unsigned short*)alloc((size_t)4096 * 2048 * 2);

  prep1_k<<<11264, 256, 0, stream>>>(x, Wq, Wkv, Wout, invf, xb, wqkvt, wot, cstab);
  gemm_bt_t<1><<<dim3(32, 24), 256, 0, stream>>>(xb, wqkvt, qkvb, 4096, 3072, 2048);
  prep2_k<<<20992, 256, 0, stream>>>(qkvb, qw, kw, cstab, qT, kT, vT);
  attn_k<<<1024, 256, 0, stream>>>(qT, kT, vT, ao);
  gemm_bt_t<0><<<dim3(32, 16), 256, 0, stream>>>(ao, wot, out, 4096, 2048, 2048);
}